// Round 1
// baseline (41580.295 us; speedup 1.0000x reference)
//
#include <hip/hip_runtime.h>
#include <math.h>

// Problem constants
#define B_   64
#define P_   196      // 14*14 pixels
#define E_   2048
#define L_   30
#define T_   29       // L-1 decode steps
#define V_   10000
#define EMB_ 512
#define AML_ 768
#define ADL_ 500
#define D_   1012     // 512+ADL
#define A_   1012
#define G4_  4048     // 4*D
#define XK_  2560     // EMB+E

__device__ __forceinline__ float sigf(float x) { return 1.f / (1.f + __expf(-x)); }
__device__ __forceinline__ float tanhf_fast(float x) { return 1.f - 2.f / (__expf(2.f * x) + 1.f); }

// ---------------- setup: stable descending argsort + masks + int outputs ----------------
__global__ void k_setup(const int* __restrict__ clen, const int* __restrict__ caps,
                        float* __restrict__ out_caps, float* __restrict__ out_dlens,
                        float* __restrict__ out_sind,
                        int* __restrict__ sort_ind, int* __restrict__ dlens_i,
                        int* __restrict__ nact, int* __restrict__ caps_s)
{
    __shared__ int lens[B_];
    int t = threadIdx.x;
    if (t < B_) lens[t] = clen[t];
    __syncthreads();
    if (t < B_) {
        int my = lens[t];
        int rank = 0;
        for (int j = 0; j < B_; ++j) {
            int lj = lens[j];
            if (lj > my || (lj == my && j < t)) rank++;  // stable descending
        }
        sort_ind[rank] = t;
    }
    __syncthreads();
    if (t < B_) {
        int orig = sort_ind[t];
        int dl = lens[orig] - 1;
        dlens_i[t] = dl;
        out_dlens[t] = (float)dl;
        out_sind[t] = (float)orig;
        for (int j = 0; j < L_; ++j) {
            int cv = caps[orig * L_ + j];
            caps_s[t * L_ + j] = cv;
            out_caps[t * L_ + j] = (float)cv;
        }
    }
    __syncthreads();
    if (t < T_) {
        int cnt = 0;
        for (int j = 0; j < B_; ++j) cnt += (dlens_i[j] > t) ? 1 : 0;
        nact[t] = cnt;
    }
}

// ---------------- zero entire output buffer ----------------
__global__ void k_zero(float4* __restrict__ p, long n4)
{
    long i = (long)blockIdx.x * 256 + threadIdx.x;
    if (i < n4) p[i] = make_float4(0.f, 0.f, 0.f, 0.f);
}

// ---------------- enc mean (transposed output [e][b]) ----------------
__global__ void k_encmean(const float* __restrict__ enc, const int* __restrict__ sort_ind,
                          float* __restrict__ emeanT)
{
    int b = blockIdx.y;
    int e = blockIdx.x * 256 + threadIdx.x;   // < 2048
    int orig = sort_ind[b];
    const float* src = enc + (long)orig * P_ * E_ + e;
    float s = 0.f;
    for (int p = 0; p < P_; ++p) s += src[(long)p * E_];
    emeanT[e * 64 + b] = s * (1.f / 196.f);
}

// ---------------- context = arts @ W_par + b_par (transposed [k][b]) ----------------
__global__ void k_ctx(const float* __restrict__ arts, const float* __restrict__ W_par,
                      const float* __restrict__ b_par, const int* __restrict__ sort_ind,
                      float* __restrict__ ctxT)
{
    int b = blockIdx.y;
    int k = blockIdx.x * 256 + threadIdx.x;
    if (k >= ADL_) return;
    int orig = sort_ind[b];
    const float* ar = arts + (long)orig * AML_;
    float s = b_par[k];
    for (int m = 0; m < AML_; ++m) s = fmaf(ar[m], W_par[m * ADL_ + k], s);
    ctxT[k * 64 + b] = s;
}

// ---------------- h0/c0: [emean|ctx] @ {W_h,W_c} ----------------
__global__ void __launch_bounds__(256) k_h0c0(
    const float* __restrict__ emeanT, const float* __restrict__ ctxT,
    const float* __restrict__ W_h, const float* __restrict__ b_h,
    const float* __restrict__ W_c, const float* __restrict__ b_c,
    float* __restrict__ hT, float* __restrict__ cT)
{
    int n = blockIdx.x * 256 + threadIdx.x;
    int nc = n < D_ ? n : D_ - 1;
    int b0 = blockIdx.y * 16;
    float ah[16], ac[16];
#pragma unroll
    for (int i = 0; i < 16; ++i) { ah[i] = 0.f; ac[i] = 0.f; }
    for (int k = 0; k < E_; ++k) {
        float wh = W_h[(long)k * D_ + nc];
        float wc = W_c[(long)k * D_ + nc];
        const float* xr = emeanT + (long)k * 64 + b0;
#pragma unroll
        for (int i = 0; i < 16; ++i) { ah[i] = fmaf(xr[i], wh, ah[i]); ac[i] = fmaf(xr[i], wc, ac[i]); }
    }
    for (int k = 0; k < ADL_; ++k) {
        float wh = W_h[(long)(E_ + k) * D_ + nc];
        float wc = W_c[(long)(E_ + k) * D_ + nc];
        const float* xr = ctxT + (long)k * 64 + b0;
#pragma unroll
        for (int i = 0; i < 16; ++i) { ah[i] = fmaf(xr[i], wh, ah[i]); ac[i] = fmaf(xr[i], wc, ac[i]); }
    }
    if (n < D_) {
        float bh = b_h[n], bc = b_c[n];
#pragma unroll
        for (int i = 0; i < 16; ++i) {
            hT[n * 64 + b0 + i] = ah[i] + bh;
            cT[n * 64 + b0 + i] = ac[i] + bc;
        }
    }
}

// ---------------- att1 = enc_sorted @ W_enc + b_enc  (row-major [row][n]) ----------------
__global__ void __launch_bounds__(256) k_att1(
    const float* __restrict__ enc, const int* __restrict__ sort_ind,
    const float* __restrict__ W_enc, const float* __restrict__ b_enc,
    float* __restrict__ att1)
{
    int n = blockIdx.x * 256 + threadIdx.x;
    int nc = n < A_ ? n : A_ - 1;
    int r0 = blockIdx.y * 16;
    long base[16];
#pragma unroll
    for (int i = 0; i < 16; ++i) {
        int r = r0 + i;
        int b = r / 196;
        int p = r - b * 196;
        base[i] = ((long)sort_ind[b] * 196 + p) * E_;
    }
    float acc[16];
#pragma unroll
    for (int i = 0; i < 16; ++i) acc[i] = 0.f;
    for (int k = 0; k < E_; ++k) {
        float w = W_enc[(long)k * A_ + nc];
#pragma unroll
        for (int i = 0; i < 16; ++i) acc[i] = fmaf(enc[base[i] + k], w, acc[i]);
    }
    if (n < A_) {
        float bv = b_enc[n];
#pragma unroll
        for (int i = 0; i < 16; ++i) att1[(long)(r0 + i) * A_ + n] = acc[i] + bv;
    }
}

// ---------------- generic skinny gemm: Y[b][n] = act(bias + sum_k XT[k][b] * W[k][n]) ----------------
template <int ACT>
__global__ void __launch_bounds__(256) k_gemm1(
    const float* __restrict__ XT, const float* __restrict__ Wm,
    const float* __restrict__ bias, float* __restrict__ Y,
    int K, int N, long ldY, long offY,
    const int* __restrict__ nact, int t)
{
    int Bact = nact[t];
    int b0 = blockIdx.y * 16;
    if (b0 >= Bact) return;
    int n = blockIdx.x * 256 + threadIdx.x;
    int nc = n < N ? n : N - 1;
    float acc[16];
#pragma unroll
    for (int i = 0; i < 16; ++i) acc[i] = 0.f;
    for (int k = 0; k < K; ++k) {
        float w = Wm[(long)k * N + nc];
        const float* xr = XT + (long)k * 64 + b0;
#pragma unroll
        for (int i = 0; i < 16; ++i) acc[i] = fmaf(xr[i], w, acc[i]);
    }
    if (n < N) {
        float bv = bias[n];
#pragma unroll
        for (int i = 0; i < 16; ++i) {
            if (b0 + i < Bact) {
                float v = acc[i] + bv;
                if (ACT == 1) v = sigf(v);
                Y[(long)(b0 + i) * ldY + offY + n] = v;
            }
        }
    }
}

// ---------------- gates = xT@W_ih + hT@W_hh + b_ih + b_hh ----------------
__global__ void __launch_bounds__(256) k_gates(
    const float* __restrict__ xT, const float* __restrict__ hT,
    const float* __restrict__ W_ih, const float* __restrict__ b_ih,
    const float* __restrict__ W_hh, const float* __restrict__ b_hh,
    float* __restrict__ gates, const int* __restrict__ nact, int t)
{
    int Bact = nact[t];
    int b0 = blockIdx.y * 16;
    if (b0 >= Bact) return;
    int n = blockIdx.x * 256 + threadIdx.x;
    int nc = n < G4_ ? n : G4_ - 1;
    float acc[16];
#pragma unroll
    for (int i = 0; i < 16; ++i) acc[i] = 0.f;
    for (int k = 0; k < XK_; ++k) {
        float w = W_ih[(long)k * G4_ + nc];
        const float* xr = xT + (long)k * 64 + b0;
#pragma unroll
        for (int i = 0; i < 16; ++i) acc[i] = fmaf(xr[i], w, acc[i]);
    }
    for (int k = 0; k < D_; ++k) {
        float w = W_hh[(long)k * G4_ + nc];
        const float* xr = hT + (long)k * 64 + b0;
#pragma unroll
        for (int i = 0; i < 16; ++i) acc[i] = fmaf(xr[i], w, acc[i]);
    }
    if (n < G4_) {
        float bv = b_ih[n] + b_hh[n];
#pragma unroll
        for (int i = 0; i < 16; ++i) gates[(long)(b0 + i) * G4_ + n] = acc[i] + bv;
    }
}

// ---------------- scores: relu(att1 + att2) @ W_full + b_full ----------------
__global__ void k_scores(const float* __restrict__ att1, const float* __restrict__ att2,
                         const float* __restrict__ W_full, const float* __restrict__ b_full,
                         float* __restrict__ scores, const int* __restrict__ nact, int t)
{
    int b = blockIdx.y;
    if (b >= nact[t]) return;
    int wv = threadIdx.x >> 6;
    int lane = threadIdx.x & 63;
    int p = blockIdx.x * 4 + wv;   // 49*4 = 196
    const float* a1 = att1 + ((long)b * P_ + p) * A_;
    const float* a2 = att2 + (long)b * A_;
    float acc = 0.f;
    for (int j = lane; j < A_; j += 64) {
        float v = a1[j] + a2[j];
        v = v > 0.f ? v : 0.f;
        acc = fmaf(v, W_full[j], acc);
    }
    for (int m = 32; m >= 1; m >>= 1) acc += __shfl_xor(acc, m);
    if (lane == 0) scores[b * P_ + p] = acc + b_full[0];
}

// ---------------- softmax over 196 + write alphas output ----------------
__global__ void k_softmax(const float* __restrict__ scores, float* __restrict__ alpha,
                          float* __restrict__ alphas_out, const int* __restrict__ nact, int t)
{
    int b = blockIdx.x;
    if (b >= nact[t]) return;
    int tid = threadIdx.x;
    __shared__ float red[4];
    float v = (tid < P_) ? scores[b * P_ + tid] : -1e30f;
    float m = v;
    for (int s = 32; s >= 1; s >>= 1) m = fmaxf(m, __shfl_xor(m, s));
    if ((tid & 63) == 0) red[tid >> 6] = m;
    __syncthreads();
    m = fmaxf(fmaxf(red[0], red[1]), fmaxf(red[2], red[3]));
    float e = (tid < P_) ? __expf(v - m) : 0.f;
    float s_ = e;
    for (int s = 32; s >= 1; s >>= 1) s_ += __shfl_xor(s_, s);
    __syncthreads();
    if ((tid & 63) == 0) red[tid >> 6] = s_;
    __syncthreads();
    s_ = red[0] + red[1] + red[2] + red[3];
    if (tid < P_) {
        float a = e / s_;
        alpha[b * P_ + tid] = a;
        alphas_out[((long)b * T_ + t) * P_ + tid] = a;
    }
}

// ---------------- awe (weighted enc sum) * sigmoid-gate + emb gather -> xT ----------------
__global__ void k_awe_x(const float* __restrict__ enc, const int* __restrict__ sort_ind,
                        const float* __restrict__ alpha, const float* __restrict__ fbuf,
                        const float* __restrict__ E_emb, const int* __restrict__ caps_s,
                        float* __restrict__ xT, const int* __restrict__ nact, int t)
{
    int b = blockIdx.y;
    if (b >= nact[t]) return;
    int tid = threadIdx.x;
    if (blockIdx.x < 8) {
        int e = blockIdx.x * 256 + tid;
        int orig = sort_ind[b];
        const float* src = enc + (long)orig * P_ * E_ + e;
        const float* al = alpha + b * P_;
        float s = 0.f;
        for (int p = 0; p < P_; ++p) s = fmaf(al[p], src[(long)p * E_], s);
        xT[(EMB_ + e) * 64 + b] = s * fbuf[(long)b * E_ + e];
    } else {
        int tok = caps_s[b * L_ + t];
        for (int k = tid; k < EMB_; k += 256)
            xT[k * 64 + b] = E_emb[(long)tok * EMB_ + k];
    }
}

// ---------------- LSTM pointwise ----------------
__global__ void k_lstm(const float* __restrict__ gates, float* __restrict__ hT,
                       float* __restrict__ cT, const int* __restrict__ nact, int t)
{
    int b = blockIdx.y;
    if (b >= nact[t]) return;
    int j = blockIdx.x * 256 + threadIdx.x;
    if (j >= D_) return;
    const float* g = gates + (long)b * G4_;
    float gi = g[j], gf = g[D_ + j], gg = g[2 * D_ + j], go = g[3 * D_ + j];
    float c = cT[j * 64 + b];
    float cn = sigf(gf) * c + sigf(gi) * tanhf_fast(gg);
    float hn = sigf(go) * tanhf_fast(cn);
    cT[j * 64 + b] = cn;
    hT[j * 64 + b] = hn;
}

extern "C" void kernel_launch(void* const* d_in, const int* in_sizes, int n_in,
                              void* d_out, int out_size, void* d_ws, size_t ws_size,
                              hipStream_t stream)
{
    const float* enc    = (const float*)d_in[0];
    const int*   caps   = (const int*)d_in[1];
    const int*   clen   = (const int*)d_in[2];
    const float* arts   = (const float*)d_in[3];
    const float* E_emb  = (const float*)d_in[6];
    const float* W_par  = (const float*)d_in[7];
    const float* b_par  = (const float*)d_in[8];
    const float* W_enc  = (const float*)d_in[9];
    const float* b_enc  = (const float*)d_in[10];
    const float* W_dec  = (const float*)d_in[11];
    const float* b_dec  = (const float*)d_in[12];
    const float* W_full = (const float*)d_in[13];
    const float* b_full = (const float*)d_in[14];
    const float* W_h    = (const float*)d_in[15];
    const float* b_h    = (const float*)d_in[16];
    const float* W_c    = (const float*)d_in[17];
    const float* b_c    = (const float*)d_in[18];
    const float* W_fb   = (const float*)d_in[19];
    const float* b_fb   = (const float*)d_in[20];
    const float* W_ih   = (const float*)d_in[21];
    const float* b_ih   = (const float*)d_in[22];
    const float* W_hh   = (const float*)d_in[23];
    const float* b_hh   = (const float*)d_in[24];
    const float* W_fc   = (const float*)d_in[25];
    const float* b_fc   = (const float*)d_in[26];

    float* out = (float*)d_out;
    float* out_preds  = out;
    float* out_caps   = out + (long)B_ * T_ * V_;
    float* out_dlens  = out_caps + B_ * L_;
    float* out_alphas = out_dlens + B_;
    float* out_sind   = out_alphas + (long)B_ * T_ * P_;

    float* ws = (float*)d_ws;
    int* sort_ind = (int*)ws;
    int* dlens_i  = sort_ind + 64;
    int* nact     = dlens_i + 64;
    int* caps_s   = nact + 32;
    float* ctxT   = ws + 2080;
    float* emeanT = ctxT + ADL_ * 64;
    float* hT     = emeanT + E_ * 64;
    float* cT     = hT + D_ * 64;
    float* att2   = cT + D_ * 64;
    float* fbuf   = att2 + D_ * 64;
    float* scores = fbuf + E_ * 64;
    float* alpha  = scores + B_ * P_;
    float* xT     = alpha + B_ * P_;
    float* gates  = xT + XK_ * 64;
    float* att1   = gates + (long)B_ * G4_;

    long n4 = ((long)B_ * T_ * V_ + B_ * L_ + B_ + (long)B_ * T_ * P_ + B_) / 4;
    k_zero<<<dim3((unsigned)((n4 + 255) / 256)), 256, 0, stream>>>((float4*)d_out, n4);
    k_setup<<<1, 64, 0, stream>>>(clen, caps, out_caps, out_dlens, out_sind,
                                  sort_ind, dlens_i, nact, caps_s);
    k_encmean<<<dim3(8, 64), 256, 0, stream>>>(enc, sort_ind, emeanT);
    k_ctx<<<dim3(2, 64), 256, 0, stream>>>(arts, W_par, b_par, sort_ind, ctxT);
    k_h0c0<<<dim3(4, 4), 256, 0, stream>>>(emeanT, ctxT, W_h, b_h, W_c, b_c, hT, cT);
    k_att1<<<dim3(4, 784), 256, 0, stream>>>(enc, sort_ind, W_enc, b_enc, att1);

    for (int t = 0; t < T_; ++t) {
        k_gemm1<0><<<dim3(4, 4), 256, 0, stream>>>(hT, W_dec, b_dec, att2, D_, D_, (long)D_, 0L, nact, t);
        k_gemm1<1><<<dim3(8, 4), 256, 0, stream>>>(hT, W_fb, b_fb, fbuf, D_, E_, (long)E_, 0L, nact, t);
        k_scores<<<dim3(49, 64), 256, 0, stream>>>(att1, att2, W_full, b_full, scores, nact, t);
        k_softmax<<<64, 256, 0, stream>>>(scores, alpha, out_alphas, nact, t);
        k_awe_x<<<dim3(9, 64), 256, 0, stream>>>(enc, sort_ind, alpha, fbuf, E_emb, caps_s, xT, nact, t);
        k_gates<<<dim3(16, 4), 256, 0, stream>>>(xT, hT, W_ih, b_ih, W_hh, b_hh, gates, nact, t);
        k_lstm<<<dim3(4, 64), 256, 0, stream>>>(gates, hT, cT, nact, t);
        k_gemm1<0><<<dim3(40, 4), 256, 0, stream>>>(hT, W_fc, b_fc, out_preds, D_, V_,
                                                    (long)T_ * V_, (long)t * V_, nact, t);
    }
}

// Round 2
// 6099.810 us; speedup vs baseline: 6.8167x; 6.8167x over previous
//
#include <hip/hip_runtime.h>
#include <math.h>

// Problem constants
#define B_   64
#define P_   196      // 14*14 pixels
#define E_   2048
#define L_   30
#define T_   29       // L-1 decode steps
#define V_   10000
#define EMB_ 512
#define AML_ 768
#define ADL_ 500
#define D_   1012     // 512+ADL
#define A_   1012
#define G4_  4048     // 4*D
#define XK_  2560     // EMB+E

typedef unsigned short u16;
typedef __attribute__((ext_vector_type(8))) short bf16x8;
typedef __attribute__((ext_vector_type(4))) float f32x4;

__device__ __forceinline__ float sigf(float x) { return 1.f / (1.f + __expf(-x)); }
__device__ __forceinline__ float tanhf_fast(float x) { return 1.f - 2.f / (__expf(2.f * x) + 1.f); }
__device__ __forceinline__ u16 f2bf(float f) {
    unsigned u = __float_as_uint(f);
    return (u16)((u + 0x7FFFu + ((u >> 16) & 1u)) >> 16);
}
__device__ __forceinline__ float bf2f(u16 v) { return __uint_as_float(((unsigned)v) << 16); }

// ---------------- setup: stable descending argsort + masks + int outputs ----------------
__global__ void k_setup(const int* __restrict__ clen, const int* __restrict__ caps,
                        float* __restrict__ out_caps, float* __restrict__ out_dlens,
                        float* __restrict__ out_sind,
                        int* __restrict__ sort_ind, int* __restrict__ dlens_i,
                        int* __restrict__ nact, int* __restrict__ caps_s)
{
    __shared__ int lens[B_];
    int t = threadIdx.x;
    if (t < B_) lens[t] = clen[t];
    __syncthreads();
    if (t < B_) {
        int my = lens[t];
        int rank = 0;
        for (int j = 0; j < B_; ++j) {
            int lj = lens[j];
            if (lj > my || (lj == my && j < t)) rank++;  // stable descending
        }
        sort_ind[rank] = t;
    }
    __syncthreads();
    if (t < B_) {
        int orig = sort_ind[t];
        int dl = lens[orig] - 1;
        dlens_i[t] = dl;
        out_dlens[t] = (float)dl;
        out_sind[t] = (float)orig;
        for (int j = 0; j < L_; ++j) {
            int cv = caps[orig * L_ + j];
            caps_s[t * L_ + j] = cv;
            out_caps[t * L_ + j] = (float)cv;
        }
    }
    __syncthreads();
    if (t < T_) {
        int cnt = 0;
        for (int j = 0; j < B_; ++j) cnt += (dlens_i[j] > t) ? 1 : 0;
        nact[t] = cnt;
    }
}

// ---------------- zero entire output buffer ----------------
__global__ void k_zero(float4* __restrict__ p, long n4)
{
    long i = (long)blockIdx.x * 256 + threadIdx.x;
    if (i < n4) p[i] = make_float4(0.f, 0.f, 0.f, 0.f);
}

// ---------------- gather + fp32->bf16 convert enc rows into sorted order ----------------
__global__ void k_cvt_enc(const float* __restrict__ enc, const int* __restrict__ sort_ind,
                          u16* __restrict__ A_bf)
{
    int row = blockIdx.y;                 // 0..12543  (b*196+p sorted)
    int b = row / 196, p = row - b * 196;
    int e4 = (blockIdx.x * 256 + threadIdx.x) * 4;   // 0..2044
    const float* src = enc + ((long)sort_ind[b] * 196 + p) * E_ + e4;
    float4 v = *(const float4*)src;
    unsigned lo = (unsigned)f2bf(v.x) | ((unsigned)f2bf(v.y) << 16);
    unsigned hi = (unsigned)f2bf(v.z) | ((unsigned)f2bf(v.w) << 16);
    uint2 pk; pk.x = lo; pk.y = hi;
    *(uint2*)(A_bf + (long)row * E_ + e4) = pk;
}

// ---------------- tiled transpose + convert: src fp32 [K][N] -> dst bf16 [Np][Kp] (pads=0) ----
__global__ void k_transpose(const float* __restrict__ src, u16* __restrict__ dst,
                            int K, int N, int Kp, int Np)
{
    __shared__ float tile[32][33];
    int n0 = blockIdx.x * 32, k0 = blockIdx.y * 32;
    int tx = threadIdx.x, ty = threadIdx.y;   // (32,8)
    for (int r = ty; r < 32; r += 8) {
        int k = k0 + r, n = n0 + tx;
        tile[r][tx] = (k < K && n < N) ? src[(long)k * N + n] : 0.f;
    }
    __syncthreads();
    for (int r = ty; r < 32; r += 8) {
        int n = n0 + r, k = k0 + tx;
        if (n < Np && k < Kp) dst[(long)n * Kp + k] = f2bf(tile[tx][r]);
    }
}

// ---------------- enc mean (transposed output [e][b]) ----------------
__global__ void k_encmean(const float* __restrict__ enc, const int* __restrict__ sort_ind,
                          float* __restrict__ emeanT)
{
    int b = blockIdx.y;
    int e = blockIdx.x * 256 + threadIdx.x;   // < 2048
    int orig = sort_ind[b];
    const float* src = enc + (long)orig * P_ * E_ + e;
    float s = 0.f;
    for (int p = 0; p < P_; ++p) s += src[(long)p * E_];
    emeanT[e * 64 + b] = s * (1.f / 196.f);
}

// ---------------- context = arts @ W_par + b_par (transposed [k][b]) ----------------
__global__ void k_ctx(const float* __restrict__ arts, const float* __restrict__ W_par,
                      const float* __restrict__ b_par, const int* __restrict__ sort_ind,
                      float* __restrict__ ctxT)
{
    int b = blockIdx.y;
    int k = blockIdx.x * 256 + threadIdx.x;
    if (k >= ADL_) return;
    int orig = sort_ind[b];
    const float* ar = arts + (long)orig * AML_;
    float s = b_par[k];
    for (int m = 0; m < AML_; ++m) s = fmaf(ar[m], W_par[m * ADL_ + k], s);
    ctxT[k * 64 + b] = s;
}

// ---------------- h0/c0: [emean|ctx] @ {W_h,W_c} -> h_bf [b][1024] bf16, c [b][1024] f32 ----
__global__ void __launch_bounds__(256) k_h0c0(
    const float* __restrict__ emeanT, const float* __restrict__ ctxT,
    const float* __restrict__ W_h, const float* __restrict__ b_h,
    const float* __restrict__ W_c, const float* __restrict__ b_c,
    u16* __restrict__ h_bf, float* __restrict__ cbuf)
{
    int n = blockIdx.x * 256 + threadIdx.x;   // 0..1023
    int nc = n < D_ ? n : D_ - 1;
    int b0 = blockIdx.y * 16;
    float ah[16], ac[16];
#pragma unroll
    for (int i = 0; i < 16; ++i) { ah[i] = 0.f; ac[i] = 0.f; }
    for (int k = 0; k < E_; ++k) {
        float wh = W_h[(long)k * D_ + nc];
        float wc = W_c[(long)k * D_ + nc];
        const float* xr = emeanT + (long)k * 64 + b0;
#pragma unroll
        for (int i = 0; i < 16; ++i) { ah[i] = fmaf(xr[i], wh, ah[i]); ac[i] = fmaf(xr[i], wc, ac[i]); }
    }
    for (int k = 0; k < ADL_; ++k) {
        float wh = W_h[(long)(E_ + k) * D_ + nc];
        float wc = W_c[(long)(E_ + k) * D_ + nc];
        const float* xr = ctxT + (long)k * 64 + b0;
#pragma unroll
        for (int i = 0; i < 16; ++i) { ah[i] = fmaf(xr[i], wh, ah[i]); ac[i] = fmaf(xr[i], wc, ac[i]); }
    }
    float bh = (n < D_) ? b_h[nc] : 0.f, bc = (n < D_) ? b_c[nc] : 0.f;
#pragma unroll
    for (int i = 0; i < 16; ++i) {
        float hv = (n < D_) ? ah[i] + bh : 0.f;
        float cv = (n < D_) ? ac[i] + bc : 0.f;
        h_bf[(long)(b0 + i) * 1024 + n] = f2bf(hv);
        cbuf[(long)(b0 + i) * 1024 + n] = cv;
    }
}

// ---------------- att1 MFMA: A_bf[12544][2048] @ WT_enc[1024][2048]^T -> att1_bf[12544][1024]
__global__ void __launch_bounds__(256) k_att1_mfma(
    const u16* __restrict__ A, const u16* __restrict__ W,
    const float* __restrict__ bias, u16* __restrict__ Yb)
{
    int w = threadIdx.x >> 6, lane = threadIdx.x & 63;
    int lr = lane & 15, lk = (lane >> 4) * 8;
    int n0 = blockIdx.x * 256 + w * 64;     // wave n-stripe (4 x 16)
    int r0 = blockIdx.y * 64;               // block m-stripe (4 x 16)
    f32x4 acc[4][4];
#pragma unroll
    for (int i = 0; i < 4; ++i)
#pragma unroll
        for (int j = 0; j < 4; ++j) acc[i][j] = (f32x4){0.f, 0.f, 0.f, 0.f};
    const u16* ap = A + (long)(r0 + lr) * E_ + lk;
    const u16* wp = W + (long)(n0 + lr) * E_ + lk;
    for (int k = 0; k < E_; k += 32) {
        bf16x8 af[4], bf[4];
#pragma unroll
        for (int mt = 0; mt < 4; ++mt) af[mt] = *(const bf16x8*)(ap + (long)mt * 16 * E_ + k);
#pragma unroll
        for (int nt = 0; nt < 4; ++nt) bf[nt] = *(const bf16x8*)(wp + (long)nt * 16 * E_ + k);
#pragma unroll
        for (int mt = 0; mt < 4; ++mt)
#pragma unroll
            for (int nt = 0; nt < 4; ++nt)
                acc[mt][nt] = __builtin_amdgcn_mfma_f32_16x16x32_bf16(af[mt], bf[nt], acc[mt][nt], 0, 0, 0);
    }
#pragma unroll
    for (int mt = 0; mt < 4; ++mt) {
#pragma unroll
        for (int nt = 0; nt < 4; ++nt) {
            int n = n0 + nt * 16 + lr;
            if (n < A_) {
                float bv = bias[n];
#pragma unroll
                for (int j = 0; j < 4; ++j) {
                    int row = r0 + mt * 16 + (lane >> 4) * 4 + j;
                    Yb[(long)row * 1024 + n] = f2bf(acc[mt][nt][j] + bv);
                }
            }
        }
    }
}

// ---------------- skinny MFMA: Y[64][N] = act(A1[64][K1]@W1^T + A2[64][K2]@W2^T + b1 + b2)
// W layout [Np][Kp] bf16 (transposed). 4 waves, each wave one 16-col stripe, M=64.
template <int ACT>
__global__ void __launch_bounds__(256) k_skinny(
    const u16* __restrict__ A1, const u16* __restrict__ W1, int K1,
    const u16* __restrict__ A2, const u16* __restrict__ W2, int K2,
    const float* __restrict__ bias1, const float* __restrict__ bias2,
    float* __restrict__ Y, long ldY, long offY, int Nmax,
    const int* __restrict__ nact, int t)
{
    int Bact = (t >= 0) ? nact[t] : B_;
    if (Bact <= 0) return;
    int mmax = (Bact + 15) >> 4;
    int w = threadIdx.x >> 6, lane = threadIdx.x & 63;
    int lr = lane & 15, lk = (lane >> 4) * 8;
    int n0 = blockIdx.x * 64 + w * 16;
    f32x4 acc[4];
#pragma unroll
    for (int m = 0; m < 4; ++m) acc[m] = (f32x4){0.f, 0.f, 0.f, 0.f};

    const u16* a1p = A1 + (long)lr * K1 + lk;
    const u16* w1p = W1 + (long)(n0 + lr) * K1 + lk;
    for (int k = 0; k < K1; k += 32) {
        bf16x8 bw = *(const bf16x8*)(w1p + k);
#pragma unroll
        for (int m = 0; m < 4; ++m)
            if (m < mmax) {
                bf16x8 aw = *(const bf16x8*)(a1p + (long)m * 16 * K1 + k);
                acc[m] = __builtin_amdgcn_mfma_f32_16x16x32_bf16(aw, bw, acc[m], 0, 0, 0);
            }
    }
    if (A2) {
        const u16* a2p = A2 + (long)lr * K2 + lk;
        const u16* w2p = W2 + (long)(n0 + lr) * K2 + lk;
        for (int k = 0; k < K2; k += 32) {
            bf16x8 bw = *(const bf16x8*)(w2p + k);
#pragma unroll
            for (int m = 0; m < 4; ++m)
                if (m < mmax) {
                    bf16x8 aw = *(const bf16x8*)(a2p + (long)m * 16 * K2 + k);
                    acc[m] = __builtin_amdgcn_mfma_f32_16x16x32_bf16(aw, bw, acc[m], 0, 0, 0);
                }
        }
    }
    int n = n0 + lr;
    if (n >= Nmax) return;
    float bv = bias1[n] + (bias2 ? bias2[n] : 0.f);
#pragma unroll
    for (int m = 0; m < 4; ++m) {
        if (m < mmax) {
#pragma unroll
            for (int j = 0; j < 4; ++j) {
                int b = m * 16 + (lane >> 4) * 4 + j;
                if (b < Bact) {
                    float v = acc[m][j] + bv;
                    if (ACT == 1) v = sigf(v);
                    Y[(long)b * ldY + offY + n] = v;
                }
            }
        }
    }
}

// ---------------- scores: relu(att1_bf + att2) @ W_full + b_full ----------------
__global__ void k_scores(const u16* __restrict__ att1, const float* __restrict__ att2,
                         const float* __restrict__ W_full, const float* __restrict__ b_full,
                         float* __restrict__ scores, const int* __restrict__ nact, int t)
{
    int b = blockIdx.y;
    if (b >= nact[t]) return;
    int wv = threadIdx.x >> 6;
    int lane = threadIdx.x & 63;
    int p = blockIdx.x * 4 + wv;   // 49*4 = 196
    const u16* a1 = att1 + ((long)b * P_ + p) * 1024;
    const float* a2 = att2 + (long)b * 1024;
    float acc = 0.f;
    for (int j2 = lane; j2 < 506; j2 += 64) {
        unsigned pk = *(const unsigned*)(a1 + 2 * j2);
        float2 a2v = *(const float2*)(a2 + 2 * j2);
        float2 wv2 = *(const float2*)(W_full + 2 * j2);
        float v0 = bf2f((u16)(pk & 0xFFFF)) + a2v.x;
        float v1 = bf2f((u16)(pk >> 16)) + a2v.y;
        v0 = v0 > 0.f ? v0 : 0.f;
        v1 = v1 > 0.f ? v1 : 0.f;
        acc = fmaf(v0, wv2.x, acc);
        acc = fmaf(v1, wv2.y, acc);
    }
    for (int m = 32; m >= 1; m >>= 1) acc += __shfl_xor(acc, m);
    if (lane == 0) scores[b * P_ + p] = acc + b_full[0];
}

// ---------------- softmax over 196 + write alphas output ----------------
__global__ void k_softmax(const float* __restrict__ scores, float* __restrict__ alpha,
                          float* __restrict__ alphas_out, const int* __restrict__ nact, int t)
{
    int b = blockIdx.x;
    if (b >= nact[t]) return;
    int tid = threadIdx.x;
    __shared__ float red[4];
    float v = (tid < P_) ? scores[b * P_ + tid] : -1e30f;
    float m = v;
    for (int s = 32; s >= 1; s >>= 1) m = fmaxf(m, __shfl_xor(m, s));
    if ((tid & 63) == 0) red[tid >> 6] = m;
    __syncthreads();
    m = fmaxf(fmaxf(red[0], red[1]), fmaxf(red[2], red[3]));
    float e = (tid < P_) ? __expf(v - m) : 0.f;
    float s_ = e;
    for (int s = 32; s >= 1; s >>= 1) s_ += __shfl_xor(s_, s);
    __syncthreads();
    if ((tid & 63) == 0) red[tid >> 6] = s_;
    __syncthreads();
    s_ = red[0] + red[1] + red[2] + red[3];
    if (tid < P_) {
        float a = e / s_;
        alpha[b * P_ + tid] = a;
        alphas_out[((long)b * T_ + t) * P_ + tid] = a;
    }
}

// ---------------- awe (weighted enc sum from A_bf) * gate + emb gather -> x_bf [b][2560] ----
__global__ void k_awe_x(const u16* __restrict__ A_bf,
                        const float* __restrict__ alpha, const float* __restrict__ fbuf,
                        const float* __restrict__ E_emb, const int* __restrict__ caps_s,
                        u16* __restrict__ x_bf, const int* __restrict__ nact, int t)
{
    int b = blockIdx.y;
    if (b >= nact[t]) return;
    int tid = threadIdx.x;
    if (blockIdx.x < 8) {
        int e = blockIdx.x * 256 + tid;
        const u16* src = A_bf + (long)b * P_ * E_ + e;
        const float* al = alpha + b * P_;
        float s = 0.f;
        for (int p = 0; p < P_; ++p) s = fmaf(al[p], bf2f(src[(long)p * E_]), s);
        x_bf[(long)b * XK_ + EMB_ + e] = f2bf(s * fbuf[(long)b * E_ + e]);
    } else {
        int tok = caps_s[b * L_ + t];
        for (int k = tid; k < EMB_; k += 256)
            x_bf[(long)b * XK_ + k] = f2bf(E_emb[(long)tok * EMB_ + k]);
    }
}

// ---------------- LSTM pointwise: gates [b][4048] f32 -> h_bf [b][1024], c [b][1024] ----
__global__ void k_lstm(const float* __restrict__ gates, u16* __restrict__ h_bf,
                       float* __restrict__ cbuf, const int* __restrict__ nact, int t)
{
    int b = blockIdx.y;
    if (b >= nact[t]) return;
    int j = blockIdx.x * 256 + threadIdx.x;
    if (j >= D_) return;
    const float* g = gates + (long)b * G4_;
    float gi = g[j], gf = g[D_ + j], gg = g[2 * D_ + j], go = g[3 * D_ + j];
    float c = cbuf[(long)b * 1024 + j];
    float cn = sigf(gf) * c + sigf(gi) * tanhf_fast(gg);
    float hn = sigf(go) * tanhf_fast(cn);
    cbuf[(long)b * 1024 + j] = cn;
    h_bf[(long)b * 1024 + j] = f2bf(hn);
}

extern "C" void kernel_launch(void* const* d_in, const int* in_sizes, int n_in,
                              void* d_out, int out_size, void* d_ws, size_t ws_size,
                              hipStream_t stream)
{
    const float* enc    = (const float*)d_in[0];
    const int*   caps   = (const int*)d_in[1];
    const int*   clen   = (const int*)d_in[2];
    const float* arts   = (const float*)d_in[3];
    const float* E_emb  = (const float*)d_in[6];
    const float* W_par  = (const float*)d_in[7];
    const float* b_par  = (const float*)d_in[8];
    const float* W_enc  = (const float*)d_in[9];
    const float* b_enc  = (const float*)d_in[10];
    const float* W_dec  = (const float*)d_in[11];
    const float* b_dec  = (const float*)d_in[12];
    const float* W_full = (const float*)d_in[13];
    const float* b_full = (const float*)d_in[14];
    const float* W_h    = (const float*)d_in[15];
    const float* b_h    = (const float*)d_in[16];
    const float* W_c    = (const float*)d_in[17];
    const float* b_c    = (const float*)d_in[18];
    const float* W_fb   = (const float*)d_in[19];
    const float* b_fb   = (const float*)d_in[20];
    const float* W_ih   = (const float*)d_in[21];
    const float* b_ih   = (const float*)d_in[22];
    const float* W_hh   = (const float*)d_in[23];
    const float* b_hh   = (const float*)d_in[24];
    const float* W_fc   = (const float*)d_in[25];
    const float* b_fc   = (const float*)d_in[26];

    float* out = (float*)d_out;
    float* out_preds  = out;
    float* out_caps   = out + (long)B_ * T_ * V_;
    float* out_dlens  = out_caps + B_ * L_;
    float* out_alphas = out_dlens + B_;
    float* out_sind   = out_alphas + (long)B_ * T_ * P_;

    // workspace layout (float units, 64-aligned)
    float* ws = (float*)d_ws;
    long o = 0;
    auto alloc = [&](long n) { long r = o; o += (n + 63) & ~63L; return r; };
    long o_ints   = alloc(2176);          // sort_ind[64], dlens[64], nact[32], caps_s[1920]
    long o_ctxT   = alloc((long)ADL_ * 64);
    long o_emeanT = alloc((long)E_ * 64);
    long o_hbf    = alloc((long)B_ * 1024 / 2);
    long o_xbf    = alloc((long)B_ * XK_ / 2);
    long o_c      = alloc((long)B_ * 1024);
    long o_att2   = alloc((long)B_ * 1024);
    long o_fbuf   = alloc((long)B_ * E_);
    long o_gates  = alloc((long)B_ * G4_);
    long o_scores = alloc((long)B_ * P_);
    long o_alpha  = alloc((long)B_ * P_);
    long o_Abf    = alloc((long)12544 * E_ / 2);
    long o_att1   = alloc((long)12544 * 1024 / 2);
    long o_wtenc  = alloc((long)1024 * 2048 / 2);
    long o_wtdec  = alloc((long)1024 * 1024 / 2);
    long o_wtfb   = alloc((long)2048 * 1024 / 2);
    long o_wtih   = alloc((long)4096 * 2560 / 2);
    long o_wthh   = alloc((long)4096 * 1024 / 2);
    long o_wtfc   = alloc((long)10048 * 1024 / 2);

    int* sort_ind = (int*)(ws + o_ints);
    int* dlens_i  = sort_ind + 64;
    int* nact     = dlens_i + 64;
    int* caps_s   = nact + 32;
    float* ctxT   = ws + o_ctxT;
    float* emeanT = ws + o_emeanT;
    u16*   h_bf   = (u16*)(ws + o_hbf);
    u16*   x_bf   = (u16*)(ws + o_xbf);
    float* cbuf   = ws + o_c;
    float* att2   = ws + o_att2;
    float* fbuf   = ws + o_fbuf;
    float* gates  = ws + o_gates;
    float* scores = ws + o_scores;
    float* alpha  = ws + o_alpha;
    u16*   A_bf   = (u16*)(ws + o_Abf);
    u16*   att1   = (u16*)(ws + o_att1);
    u16*   WT_enc = (u16*)(ws + o_wtenc);
    u16*   WT_dec = (u16*)(ws + o_wtdec);
    u16*   WT_fb  = (u16*)(ws + o_wtfb);
    u16*   WT_ih  = (u16*)(ws + o_wtih);
    u16*   WT_hh  = (u16*)(ws + o_wthh);
    u16*   WT_fc  = (u16*)(ws + o_wtfc);

    long n4 = ((long)B_ * T_ * V_ + B_ * L_ + B_ + (long)B_ * T_ * P_ + B_) / 4;
    k_zero<<<dim3((unsigned)((n4 + 255) / 256)), 256, 0, stream>>>((float4*)d_out, n4);
    k_setup<<<1, 64, 0, stream>>>(clen, caps, out_caps, out_dlens, out_sind,
                                  sort_ind, dlens_i, nact, caps_s);
    k_cvt_enc<<<dim3(2, 12544), 256, 0, stream>>>(enc, sort_ind, A_bf);

    dim3 tb(32, 8);
    k_transpose<<<dim3(1024/32, 2048/32), tb, 0, stream>>>(W_enc, WT_enc, 2048, 1012, 2048, 1024);
    k_transpose<<<dim3(1024/32, 1024/32), tb, 0, stream>>>(W_dec, WT_dec, 1012, 1012, 1024, 1024);
    k_transpose<<<dim3(2048/32, 1024/32), tb, 0, stream>>>(W_fb, WT_fb, 1012, 2048, 1024, 2048);
    k_transpose<<<dim3(4096/32, 2560/32), tb, 0, stream>>>(W_ih, WT_ih, 2560, 4048, 2560, 4096);
    k_transpose<<<dim3(4096/32, 1024/32), tb, 0, stream>>>(W_hh, WT_hh, 1012, 4048, 1024, 4096);
    k_transpose<<<dim3(10048/32, 1024/32), tb, 0, stream>>>(W_fc, WT_fc, 1012, 10000, 1024, 10048);

    k_encmean<<<dim3(8, 64), 256, 0, stream>>>(enc, sort_ind, emeanT);
    k_ctx<<<dim3(2, 64), 256, 0, stream>>>(arts, W_par, b_par, sort_ind, ctxT);
    k_h0c0<<<dim3(4, 4), 256, 0, stream>>>(emeanT, ctxT, W_h, b_h, W_c, b_c, h_bf, cbuf);
    k_att1_mfma<<<dim3(4, 196), 256, 0, stream>>>(A_bf, WT_enc, b_enc, att1);

    for (int t = 0; t < T_; ++t) {
        k_skinny<0><<<dim3(16), 256, 0, stream>>>(h_bf, WT_dec, 1024, (const u16*)0, (const u16*)0, 0,
                                                  b_dec, (const float*)0, att2, 1024L, 0L, A_, nact, t);
        k_skinny<1><<<dim3(32), 256, 0, stream>>>(h_bf, WT_fb, 1024, (const u16*)0, (const u16*)0, 0,
                                                  b_fb, (const float*)0, fbuf, (long)E_, 0L, E_, nact, t);
        k_scores<<<dim3(49, 64), 256, 0, stream>>>(att1, att2, W_full, b_full, scores, nact, t);
        k_softmax<<<64, 256, 0, stream>>>(scores, alpha, out_alphas, nact, t);
        k_awe_x<<<dim3(9, 64), 256, 0, stream>>>(A_bf, alpha, fbuf, E_emb, caps_s, x_bf, nact, t);
        k_skinny<0><<<dim3(64), 256, 0, stream>>>(x_bf, WT_ih, 2560, h_bf, WT_hh, 1024,
                                                  b_ih, b_hh, gates, (long)G4_, 0L, G4_, nact, t);
        k_lstm<<<dim3(4, 64), 256, 0, stream>>>(gates, h_bf, cbuf, nact, t);
        k_skinny<0><<<dim3(157), 256, 0, stream>>>(h_bf, WT_fc, 1024, (const u16*)0, (const u16*)0, 0,
                                                   b_fc, (const float*)0, out_preds, (long)T_ * V_,
                                                   (long)t * V_, V_, nact, t);
    }
}